// Round 6
// baseline (232.783 us; speedup 1.0000x reference)
//
#include <hip/hip_runtime.h>

// DispNetC correlation volume: out[b,d,h,w] = mean_c L[b,c,h,w]*R[b,c,h,w-d]
// for w>=d, else 0.  f32 in / f32 out.
//
// R11: 52us barrier-synced baseline. R15: full async global_load_lds ring
//   pipeline (counted vmcnt, 3-deep) = 49us -- NULL vs R11. Within-block
//   overlap is NOT the limiter. Invariant of all ~50us variants: 1 block/CU,
//   one barrier domain -> every barrier/vmcnt idles the whole CU's memory
//   stream. m97-GEMM sustains ~6.8 TB/s through the same DMA path with ~3
//   independent blocks/CU covering each other's stalls.
// R16 (this): 2 independent pipelines per CU.
//   - c-split: block = (b, h2, c-half of 128). 512 blocks x 512 threads
//     (8 waves). LDS = ring 3x16KB + fin 32KB = 80KB -> exactly 2 blocks/CU,
//     two independent barrier domains interleaving their HBM bursts.
//   - Partial sums combined with atomicAdd (2 addends/elem, f32 add commutes
//     -> bit-deterministic). out zero-initialized by hipMemsetAsync (graph-
//     capture-safe; harness uses it itself); triangle-fill loop deleted.
//   - Staging/transpose/swizzle/MFMA band map identical to R15's verified
//     machinery, re-parameterized: 16 subs x 8c, chunk = 4 subs (K=32),
//     4 chunks; MFMA 52 instances over 8 waves (7 li slots, ragged last).

typedef __attribute__((ext_vector_type(8))) short short8;   // MFMA A/B frag
typedef __attribute__((ext_vector_type(4))) float floatx4;  // MFMA C/D frag

#define NB 8
#define NC 256
#define NH 64
#define NWD 128
#define ND 40
// s_waitcnt imm: vm[3:0] | exp[6:4]=7 | lgkm[11:8] | vm[5:4]@[15:14]
#define WCNT(vm, lgkm) (((vm) & 15) | (((vm) >> 4) << 14) | (7 << 4) | ((lgkm) << 8))

// async global->LDS, 16B per lane: global src per-lane, LDS dest wave-uniform
// base (HW writes base + lane*16).
__device__ __forceinline__ void gll16(const float* g, const float* l) {
  __builtin_amdgcn_global_load_lds(
      (const __attribute__((address_space(1))) unsigned int*)g,
      (__attribute__((address_space(3))) unsigned int*)l, 16, 0, 0);
}

// LDS map (bytes):
//   sbuf ring: 3 x 16384   f32 [arr][c'8] rows of 1KB ([hh][w])  : 0
//   fin      : 32768       u16 [arr][hh][w][32c swizzled]        : 49152
// total 81920 B -> 2 blocks/CU, 16 waves/CU.

// Issue sub-stage s (8 channels, both arrays) into ring buffer bi.
// 2 instrs/wave (8 waves): rows r = 2wv, 2wv+1; r = arr*8 + c''. Each instr
// stages global rows (c, h0)+(c, h1) = 1KB contiguous -> LDS row r (linear).
#define ISSUE_SUB(s, bi)                                                       \
  do {                                                                         \
    _Pragma("unroll")                                                          \
    for (int j_ = 0; j_ < 2; ++j_) {                                           \
      const int r_ = wv * 2 + j_;              /* 0..15 */                     \
      const int c_ = cbase + (s) * 8 + (r_ & 7);                               \
      const float* g_ = ((r_ >> 3) ? Rg : Lg) + gbase + (size_t)c_ * HW;       \
      gll16(g_ + lane * 4, sbuf + (bi) * 4096 + r_ * 256);                     \
    }                                                                          \
  } while (0)

// Transpose sub-stage s from ring buffer bi into fin.
// 512 threads = 512 cols (tarr, thh, tw). 8x ds_read_b32 stride 1KB (bank =
// tw%32 over lanes -> 2/bank, free), pack bf16 round-half-up, one b128 write
// at swizzled (gu ^ (tw&3)) slot; gu = s&3 (8-c group within K=32 chunk).
#define TRANSPOSE_SUB(s, bi)                                                   \
  do {                                                                         \
    const float* sb_ = sbuf + (bi) * 4096 + tarr * 2048 + thh * 128 + tw;      \
    float f_[8];                                                               \
    _Pragma("unroll")                                                          \
    for (int i_ = 0; i_ < 8; ++i_) f_[i_] = sb_[i_ * 256];                     \
    unsigned int u_[4];                                                        \
    _Pragma("unroll")                                                          \
    for (int i_ = 0; i_ < 4; ++i_)                                             \
      u_[i_] = ((__float_as_uint(f_[2 * i_]) + 0x8000u) >> 16) |               \
               ((__float_as_uint(f_[2 * i_ + 1]) + 0x8000u) & 0xFFFF0000u);    \
    const int gu_ = (s) & 3;                                                   \
    *(uint4*)(fin + tarr * 8192 + thh * 4096 + tw * 32 +                       \
              ((gu_ ^ (tw & 3)) << 3)) =                                       \
        make_uint4(u_[0], u_[1], u_[2], u_[3]);                                \
  } while (0)

// 52 MFMA instances (2h x 26 band tiles) over 8 waves, one K=32 step.
// li 0..6: inst = wv + 8*li (ragged: li=6 valid only for wv<4; wave-uniform).
#define MFMA_CHUNK32()                                                         \
  do {                                                                         \
    const unsigned short* Lb = fin;                                            \
    const unsigned short* Rb = fin + 8192;                                     \
    _Pragma("unroll")                                                          \
    for (int li = 0; li < 7; ++li) {                                           \
      const int inst = wv + (li << 3);                                         \
      if (inst >= 52) break;                                                   \
      const int hh   = (inst >= 26) ? 1 : 0;                                   \
      const int tile = inst - hh * 26;                                         \
      const int i  = (tile < 8) ? tile : (tile < 15) ? tile - 8                \
                   : (tile < 21) ? tile - 15 : tile - 21;                      \
      const int k  = (tile < 8) ? 0 : (tile < 15) ? 1                          \
                   : (tile < 21) ? 2 : 3;                                      \
      const int j  = i + k;                                                    \
      const int ra = 16 * i + m;                                               \
      const int rb = 16 * j + m;                                               \
      const short8 av =                                                        \
          *(const short8*)(Rb + hh * 4096 + ra * 32 + ((q ^ (ra & 3)) << 3));  \
      const short8 bv =                                                        \
          *(const short8*)(Lb + hh * 4096 + rb * 32 + ((q ^ (rb & 3)) << 3));  \
      acc[li] =                                                                \
          __builtin_amdgcn_mfma_f32_16x16x32_bf16(av, bv, acc[li], 0, 0, 0);   \
    }                                                                          \
  } while (0)

__global__ __launch_bounds__(512, 4) void corr_split(
    const float* __restrict__ Lg,
    const float* __restrict__ Rg,
    float* __restrict__ out)
{
  __shared__ __align__(16) unsigned char smem[81920];
  float* sbuf = (float*)smem;                                // 3 x 4096 f32
  unsigned short* fin = (unsigned short*)(smem + 49152);     // 16384 u16

  const int blk  = blockIdx.x;
  const int b    = blk & 7;          // XCD de-camping remap (kept)
  const int rr   = blk >> 3;
  const int h2   = rr & 31;
  const int ch   = rr >> 5;          // c-half 0/1
  const int tid  = threadIdx.x;
  const int lane = tid & 63;
  const int wv   = tid >> 6;         // 0..7
  const int m    = lane & 15;
  const int q    = lane >> 4;

  // transpose thread role (512 cols)
  const int tarr = tid >> 8;
  const int thh  = (tid >> 7) & 1;
  const int tw   = tid & 127;

  const size_t HW    = (size_t)NH * NWD;
  const size_t gbase = (size_t)b * NC * HW + (size_t)(h2 * 2) * NWD;
  const int cbase    = ch * 128;

  floatx4 acc[7];
  #pragma unroll
  for (int i = 0; i < 7; ++i) acc[i] = (floatx4){0.f, 0.f, 0.f, 0.f};

  // prologue: subs 0,1 in flight (4 outstanding vm ops/wave)
  ISSUE_SUB(0, 0);
  ISSUE_SUB(1, 1);

  for (int s = 0; s < 15; ++s) {
    // own sub-s loads complete (leave the 2 newer in flight), then barrier:
    // all waves' sub-s staging visible AND all transpose(s-1) reads retired.
    __builtin_amdgcn_s_waitcnt(WCNT(2, 15));
    __builtin_amdgcn_s_barrier();
    __builtin_amdgcn_sched_barrier(0);

    if (s < 14) ISSUE_SUB(s + 2, (s + 2) % 3);   // overwrites buf read at s-1: safe
    TRANSPOSE_SUB(s, s % 3);

    if ((s & 3) == 3) {   // chunk boundary: fin (32c) complete -> MFMA
      __builtin_amdgcn_s_waitcnt(WCNT(63, 0));   // fin writes visible (lgkm only!)
      __builtin_amdgcn_s_barrier();
      __builtin_amdgcn_sched_barrier(0);
      MFMA_CHUNK32();
      __builtin_amdgcn_s_barrier();              // fin free for next chunk
      __builtin_amdgcn_sched_barrier(0);
    }
  }

  // ---- peeled s = 15: no loads in flight beyond our own last sub ----
  __builtin_amdgcn_s_waitcnt(WCNT(0, 15));
  __builtin_amdgcn_s_barrier();
  __builtin_amdgcn_sched_barrier(0);
  TRANSPOSE_SUB(15, 0);                          // 15 % 3 == 0
  __builtin_amdgcn_s_waitcnt(WCNT(63, 0));       // fin writes visible
  __builtin_amdgcn_s_barrier();
  __builtin_amdgcn_sched_barrier(0);
  MFMA_CHUNK32();

  // ---- epilogue: atomic partial-sum combine (2 c-halves per out element).
  // D layout col=lane&15 (w in tile j), row=q*4+r (w' in tile i).
  // w<d triangle stays at the memset zeros.
  #pragma unroll
  for (int li = 0; li < 7; ++li) {
    const int inst = wv + (li << 3);
    if (inst >= 52) break;
    const int hh   = (inst >= 26) ? 1 : 0;
    const int tile = inst - hh * 26;
    const int i  = (tile < 8) ? tile : (tile < 15) ? tile - 8
                 : (tile < 21) ? tile - 15 : tile - 21;
    const int k  = (tile < 8) ? 0 : (tile < 15) ? 1 : (tile < 21) ? 2 : 3;
    const int j  = i + k;
    const int h  = h2 * 2 + hh;
    const int w  = 16 * j + m;
    #pragma unroll
    for (int r = 0; r < 4; ++r) {
      const int wp = 16 * i + q * 4 + r;
      const int d  = w - wp;
      if (d >= 0 && d < ND)
        atomicAdd(&out[(((size_t)b * ND + d) * NH + h) * NWD + w],
                  acc[li][r] * 0.00390625f);
    }
  }
}

extern "C" void kernel_launch(void* const* d_in, const int* in_sizes, int n_in,
                              void* d_out, int out_size, void* d_ws, size_t ws_size,
                              hipStream_t stream) {
  hipMemsetAsync(d_out, 0, (size_t)out_size, stream);
  corr_split<<<dim3(512), dim3(512), 0, stream>>>(
      (const float*)d_in[0], (const float*)d_in[1], (float*)d_out);
}

// Round 7
// 149.883 us; speedup vs baseline: 1.5531x; 1.5531x over previous
//
#include <hip/hip_runtime.h>

// DispNetC correlation volume: out[b,d,h,w] = mean_c L[b,c,h,w]*R[b,c,h,w-d]
// for w>=d, else 0.  f32 in / f32 out.
//
// R11 52us / R15 async ring 49us: within-block overlap NULL. All ~50us
//   variants share: 1 block/CU, one barrier domain -> barrier/vmcnt idles the
//   whole CU's memory stream. m97-GEMM sustains ~6.8TB/s through the same
//   global_load_lds path with ~3 blocks/CU covering each other's stalls.
// R16 FAILED (129us): c-split gave 2 blocks/CU but atomicAdd combine added
//   86MB of RMW traffic -> dominated. Lesson: c-reduction stays in-block.
// R17 (this): 2 independent pipelines/CU WITHOUT atomics: block = (b, h).
//   512 blocks x 512 threads (8 waves). Outputs disjoint -> plain stores.
//   LDS = ring 3x16KB + fin 16KB = 64KB -> 2 blocks/CU, two independent
//   barrier domains interleaving their HBM bursts.
//   512B c-rows staged via per-lane DMA src: lanes 0-31 -> row c, lanes
//   32-63 -> row c+1 (global src of global_load_lds is per-lane; only the
//   LDS dest must be linear). Everything else is R15's verified machinery:
//   16 subs x 16c, 3-deep counted-vmcnt ring, transpose+bf16 pack with
//   gu^(w&3) swizzle, MFMA every 2 subs (26 band tiles over 8 waves).

typedef __attribute__((ext_vector_type(8))) short short8;   // MFMA A/B frag
typedef __attribute__((ext_vector_type(4))) float floatx4;  // MFMA C/D frag

#define NB 8
#define NC 256
#define NH 64
#define NWD 128
#define ND 40
// s_waitcnt imm: vm[3:0] | exp[6:4]=7 | lgkm[11:8] | vm[5:4]@[15:14]
#define WCNT(vm, lgkm) (((vm) & 15) | (((vm) >> 4) << 14) | (7 << 4) | ((lgkm) << 8))

// async global->LDS, 16B per lane: global src PER-LANE, LDS dest wave-uniform
// base (HW writes base + lane*16).
__device__ __forceinline__ void gll16(const float* g, const float* l) {
  __builtin_amdgcn_global_load_lds(
      (const __attribute__((address_space(1))) unsigned int*)g,
      (__attribute__((address_space(3))) unsigned int*)l, 16, 0, 0);
}

// LDS map (bytes):
//   sbuf ring: 3 x 16384   f32 rows [arr*16 + c''][128 w]   : 0
//   fin      : 16384       u16 [arr][w][32c swizzled]       : 49152
// total 65536 B -> 2 blocks/CU, 16 waves/CU in 2 independent domains.

// Issue sub-stage s (16 channels, both arrays) into ring buffer bi.
// 2 instrs/wave (8 waves): instr idx = wv*2+j_ (0..15); arr = idx>>3,
// c-pair = (idx&7)*2. Lanes 0-31 read row (c, h) 512B, lanes 32-63 row
// (c+1, h); LDS dest linear -> rows land consecutively.
#define ISSUE_SUB(s, bi)                                                       \
  do {                                                                         \
    _Pragma("unroll")                                                          \
    for (int j_ = 0; j_ < 2; ++j_) {                                           \
      const int idx_ = wv * 2 + j_;            /* 0..15 */                     \
      const int arr_ = idx_ >> 3;                                              \
      const int cp_  = (idx_ & 7) * 2;                                         \
      const int c_   = (s) * 16 + cp_ + (lane >> 5);                           \
      const float* g_ = (arr_ ? Rg : Lg) + gbase + (size_t)c_ * HW             \
                      + (lane & 31) * 4;                                       \
      gll16(g_, sbuf + (bi) * 4096 + (arr_ * 16 + cp_) * 128);                 \
    }                                                                          \
  } while (0)

// Transpose sub-stage s from ring buffer bi into fin.
// 512 threads = 512 cols (tarr, tw, thalf). 8x ds_read_b32 stride 512B
// (bank = tw%32, 2 lanes/bank = free), pack bf16 round-half-up, one b128
// write at swizzled (gu ^ (tw&3)) slot; gu = (s&1)*2 + thalf.
#define TRANSPOSE_SUB(s, bi)                                                   \
  do {                                                                         \
    const float* sb_ = sbuf + (bi) * 4096 + (tarr * 16 + thalf * 8) * 128 + tw;\
    float f_[8];                                                               \
    _Pragma("unroll")                                                          \
    for (int i_ = 0; i_ < 8; ++i_) f_[i_] = sb_[i_ * 128];                     \
    unsigned int u_[4];                                                        \
    _Pragma("unroll")                                                          \
    for (int i_ = 0; i_ < 4; ++i_)                                             \
      u_[i_] = ((__float_as_uint(f_[2 * i_]) + 0x8000u) >> 16) |               \
               ((__float_as_uint(f_[2 * i_ + 1]) + 0x8000u) & 0xFFFF0000u);    \
    const int gu_ = ((s) & 1) * 2 + thalf;                                     \
    *(uint4*)(fin + tarr * 4096 + tw * 32 + ((gu_ ^ (tw & 3)) << 3)) =         \
        make_uint4(u_[0], u_[1], u_[2], u_[3]);                                \
  } while (0)

// 26 MFMA band-tile instances over 8 waves, one K=32 step.
// li 0..3: inst = wv + 8*li (ragged last: wave-uniform break).
#define MFMA_CHUNK26()                                                         \
  do {                                                                         \
    const unsigned short* Lb = fin;                                            \
    const unsigned short* Rb = fin + 4096;                                     \
    _Pragma("unroll")                                                          \
    for (int li = 0; li < 4; ++li) {                                           \
      const int inst = wv + (li << 3);                                         \
      if (inst >= 26) break;                                                   \
      const int i  = (inst < 8) ? inst : (inst < 15) ? inst - 8                \
                   : (inst < 21) ? inst - 15 : inst - 21;                      \
      const int k  = (inst < 8) ? 0 : (inst < 15) ? 1                          \
                   : (inst < 21) ? 2 : 3;                                      \
      const int j  = i + k;                                                    \
      const int ra = 16 * i + m;                                               \
      const int rb = 16 * j + m;                                               \
      const short8 av =                                                        \
          *(const short8*)(Rb + ra * 32 + ((q ^ (ra & 3)) << 3));              \
      const short8 bv =                                                        \
          *(const short8*)(Lb + rb * 32 + ((q ^ (rb & 3)) << 3));              \
      acc[li] =                                                                \
          __builtin_amdgcn_mfma_f32_16x16x32_bf16(av, bv, acc[li], 0, 0, 0);   \
    }                                                                          \
  } while (0)

__global__ __launch_bounds__(512, 4) void corr_hsplit(
    const float* __restrict__ Lg,
    const float* __restrict__ Rg,
    float* __restrict__ out)
{
  __shared__ __align__(16) unsigned char smem[65536];
  float* sbuf = (float*)smem;                                // 3 x 4096 f32
  unsigned short* fin = (unsigned short*)(smem + 49152);     // 8192 u16

  const int blk  = blockIdx.x;
  const int b    = blk & 7;          // XCD de-camping remap (kept)
  const int h    = blk >> 3;         // 0..63
  const int tid  = threadIdx.x;
  const int lane = tid & 63;
  const int wv   = tid >> 6;         // 0..7
  const int m    = lane & 15;
  const int q    = lane >> 4;

  // transpose thread role (512 cols)
  const int tarr  = tid >> 8;        // 0/1 = L/R
  const int thalf = (tid >> 7) & 1;  // 8-c half of the sub
  const int tw    = tid & 127;

  const size_t HW    = (size_t)NH * NWD;
  const size_t gbase = (size_t)b * NC * HW + (size_t)h * NWD;

  floatx4 acc[4];
  #pragma unroll
  for (int i = 0; i < 4; ++i) acc[i] = (floatx4){0.f, 0.f, 0.f, 0.f};

  // prologue: subs 0,1 in flight (4 outstanding vm ops/wave)
  ISSUE_SUB(0, 0);
  ISSUE_SUB(1, 1);

  for (int s = 0; s < 15; ++s) {
    // own sub-s loads complete (leave the 2 newer in flight), then barrier:
    // all waves' sub-s staging visible AND all transpose(s-1) reads retired.
    __builtin_amdgcn_s_waitcnt(WCNT(2, 15));
    __builtin_amdgcn_s_barrier();
    __builtin_amdgcn_sched_barrier(0);

    if (s < 14) ISSUE_SUB(s + 2, (s + 2) % 3);   // overwrites buf read at s-1: safe
    TRANSPOSE_SUB(s, s % 3);

    if (s & 1) {   // chunk boundary: fin (32c) complete -> MFMA
      __builtin_amdgcn_s_waitcnt(WCNT(63, 0));   // fin writes visible (lgkm only!)
      __builtin_amdgcn_s_barrier();
      __builtin_amdgcn_sched_barrier(0);
      MFMA_CHUNK26();
      __builtin_amdgcn_s_barrier();              // fin free for next chunk
      __builtin_amdgcn_sched_barrier(0);
    }
  }

  // ---- peeled s = 15: no loads in flight beyond our own last sub ----
  __builtin_amdgcn_s_waitcnt(WCNT(0, 15));
  __builtin_amdgcn_s_barrier();
  __builtin_amdgcn_sched_barrier(0);
  TRANSPOSE_SUB(15, 0);                          // 15 % 3 == 0
  __builtin_amdgcn_s_waitcnt(WCNT(63, 0));       // fin writes visible
  __builtin_amdgcn_s_barrier();
  __builtin_amdgcn_sched_barrier(0);
  MFMA_CHUNK26();

  // ---- epilogue: D layout col=lane&15 (w in tile j), row=q*4+r (w' in tile i) ----
  #pragma unroll
  for (int li = 0; li < 4; ++li) {
    const int inst = wv + (li << 3);
    if (inst >= 26) break;
    const int i  = (inst < 8) ? inst : (inst < 15) ? inst - 8
                 : (inst < 21) ? inst - 15 : inst - 21;
    const int k  = (inst < 8) ? 0 : (inst < 15) ? 1 : (inst < 21) ? 2 : 3;
    const int j  = i + k;
    const int w  = 16 * j + m;
    #pragma unroll
    for (int r = 0; r < 4; ++r) {
      const int wp = 16 * i + q * 4 + r;
      const int d  = w - wp;
      if (d >= 0 && d < ND)
        out[(((size_t)b * ND + d) * NH + h) * NWD + w] = acc[li][r] * 0.00390625f;
    }
  }

  // ---- zero-fill the w<d triangle for this h (d_out poisoned each launch) ----
  for (int t = tid; t < ND * ND; t += 512) {
    const int d = t / ND;
    const int w = t - d * ND;
    if (w < d)
      out[(((size_t)b * ND + d) * NH + h) * NWD + w] = 0.0f;
  }
}

extern "C" void kernel_launch(void* const* d_in, const int* in_sizes, int n_in,
                              void* d_out, int out_size, void* d_ws, size_t ws_size,
                              hipStream_t stream) {
  corr_hsplit<<<dim3(512), dim3(512), 0, stream>>>(
      (const float*)d_in[0], (const float*)d_in[1], (float*)d_out);
}